// Round 15
// baseline (278.607 us; speedup 1.0000x reference)
//
#include <hip/hip_runtime.h>

#define S_LEN 2048
#define DM 2048
#define NH 16
#define DK 128
#define BB 2
#define BH (BB*NH)
#define GK 2048

typedef float f32x4 __attribute__((ext_vector_type(4)));
typedef float f32x16 __attribute__((ext_vector_type(16)));
typedef __bf16 bf16x8 __attribute__((ext_vector_type(8)));
typedef __bf16 bf16x2 __attribute__((ext_vector_type(2)));
typedef unsigned int u32;

#define AS1 __attribute__((address_space(1)))
#define AS3 __attribute__((address_space(3)))

__device__ inline void gload16(const void* g, void* l){
  __builtin_amdgcn_global_load_lds((AS1 const u32*)g, (AS3 u32*)l, 16, 0, 0);
}

__device__ inline ushort f2bf(float f){
  __bf16 h = (__bf16)f;
  ushort u;
  __builtin_memcpy(&u, &h, 2);
  return u;
}

__device__ inline u32 cvtpk(float a, float b){
  bf16x2 p; p[0] = (__bf16)a; p[1] = (__bf16)b;
  u32 r; __builtin_memcpy(&r, &p, 4); return r;
}

// ---------------- all fp32->bf16 conversions (x + 4 weights) in one launch ----------------
__global__ void k_conv(const float* __restrict__ x, const float* __restrict__ wq,
                       const float* __restrict__ wk, const float* __restrict__ wv,
                       const float* __restrict__ wo4,
                       ushort* __restrict__ xb, ushort* __restrict__ dqkv,
                       ushort* __restrict__ dwo){
  int i = blockIdx.x * 256 + threadIdx.x;    // 0 .. 6M-1 (float4 units)
  int sel = i >> 20;
  int off = i & ((1 << 20) - 1);
  const float* s; ushort* d;
  if (sel < 2){ s = x + ((size_t)sel << 22); d = xb + ((size_t)sel << 22); }
  else if (sel == 2){ s = wq; d = dqkv; }
  else if (sel == 3){ s = wk; d = dqkv + (size_t)DM * DM; }
  else if (sel == 4){ s = wv; d = dqkv + (size_t)2 * DM * DM; }
  else { s = wo4; d = dwo; }
  float4 v = reinterpret_cast<const float4*>(s)[off];
  ushort4 o;
  o.x = f2bf(v.x); o.y = f2bf(v.y); o.z = f2bf(v.z); o.w = f2bf(v.w);
  reinterpret_cast<ushort4*>(d)[off] = o;
}

// ---------------- rope cos/sin table [S][64] as float2 {cos,sin} ----------------
__global__ void k_rope_table(const int* __restrict__ pos, float2* __restrict__ cs){
  int idx = blockIdx.x * 256 + threadIdx.x;
  if (idx >= S_LEN * 64) return;
  int s = idx >> 6, i = idx & 63;
  float inv = expf(-0.14391156831212787f * (float)i);   // 10000^(-i/64)
  float f = (float)pos[s] * inv;
  cs[idx] = make_float2(cosf(f), sinf(f));
}

#define SBAR() do{ __builtin_amdgcn_s_barrier(); __builtin_amdgcn_sched_barrier(0); }while(0)
#define VMC(n) asm volatile("s_waitcnt vmcnt(" #n ")" ::: "memory")

// ================= Q+K GEMM: 256x256 tile, BK=64, 8 waves, 8-phase =================
#define STG(slot, srcp, tks, khh) do{ \
  const ushort* _s = (srcp) + (tks)*64 + (khh)*32; \
  gload16(_s,                    lds + (slot)*8192 + wid*512); \
  gload16(_s + (size_t)128*GK,   lds + (slot)*8192 + 4096 + wid*512); \
}while(0)

#define RD_A(slot, mh) do{ \
  af[0] = *reinterpret_cast<const bf16x8*>(ldsc + (slot)*16384 + wm*8192 + ((mh)*4+0)*1024 + frA); \
  af[1] = *reinterpret_cast<const bf16x8*>(ldsc + (slot)*16384 + wm*8192 + ((mh)*4+1)*1024 + frA); \
  af[2] = *reinterpret_cast<const bf16x8*>(ldsc + (slot)*16384 + wm*8192 + ((mh)*4+2)*1024 + frA); \
  af[3] = *reinterpret_cast<const bf16x8*>(ldsc + (slot)*16384 + wm*8192 + ((mh)*4+3)*1024 + frA); \
}while(0)

#define RD_B(slot) do{ \
  bfr[0] = *reinterpret_cast<const bf16x8*>(ldsc + (slot)*16384 + wn*4096 + 0*1024 + frA); \
  bfr[1] = *reinterpret_cast<const bf16x8*>(ldsc + (slot)*16384 + wn*4096 + 1*1024 + frA); \
  bfr[2] = *reinterpret_cast<const bf16x8*>(ldsc + (slot)*16384 + wn*4096 + 2*1024 + frA); \
  bfr[3] = *reinterpret_cast<const bf16x8*>(ldsc + (slot)*16384 + wn*4096 + 3*1024 + frA); \
}while(0)

#define MM(mh) do{ \
  __builtin_amdgcn_s_setprio(1); \
  _Pragma("unroll") \
  for (int mf2 = 0; mf2 < 4; mf2++) \
    _Pragma("unroll") \
    for (int nf = 0; nf < 4; nf++) \
      acc[(mh)*4+mf2][nf] = __builtin_amdgcn_mfma_f32_16x16x32_bf16(af[mf2], bfr[nf], acc[(mh)*4+mf2][nf], 0, 0, 0); \
  __builtin_amdgcn_s_setprio(0); \
}while(0)

__launch_bounds__(512, 2)
__global__ void k_gemm_qk(const ushort* __restrict__ A, const ushort* __restrict__ Bt,
                          const float2* __restrict__ cs,
                          ushort* __restrict__ Qh, ushort* __restrict__ Kh){
  __shared__ short lds[65536];   // 128 KiB: 8 half-slots x 16 KB
  const int tid = threadIdx.x, lane = tid & 63, wid = tid >> 6;
  const int wm = wid >> 2, wn = wid & 3;
  const int fr = lane & 15, fq = lane >> 4;

  const int bid = blockIdx.x;                  // 256 = 8*32, bijective XCD swizzle
  const int b2 = (bid & 7) * 32 + (bid >> 3);
  const int by = b2 >> 4, bx = b2 & 15;

  const int rbase = wid * 16 + (lane >> 2);
  const int kup = ((lane & 3) ^ ((lane >> 3) & 3)) * 8;
  const ushort* pa = A  + (size_t)(by * 256 + rbase) * GK + kup;
  const ushort* pb = Bt + (size_t)(bx * 256 + rbase) * GK + kup;

  const char* ldsc = (const char*)lds;
  const int frA = fr * 64 + ((fq * 16) ^ (((fr >> 1) & 3) << 4));

  f32x4 acc[8][4] = {};
  bf16x8 af[4], bfr[4];

  STG(0, pa, 0, 0); STG(1, pb, 0, 0); STG(2, pa, 0, 1); STG(3, pb, 0, 1);
  STG(4, pa, 1, 0); STG(5, pb, 1, 0);
  VMC(8);
  SBAR();

  #pragma unroll 1
  for (int it = 0; it < 16; ++it){
    const int tb  = 2 * it + 1;
    const int tn  = (2 * it + 2 < 32) ? 2 * it + 2 : 31;
    const int tn1 = (2 * it + 3 < 32) ? 2 * it + 3 : 31;
    RD_A(0, 0); RD_B(1); STG(6, pa, tb, 1);           SBAR(); MM(0); SBAR();
    RD_A(0, 1);          STG(7, pb, tb, 1);  VMC(6);  SBAR(); MM(1); SBAR();
    RD_A(2, 0); RD_B(3); STG(0, pa, tn, 0);           SBAR(); MM(0); SBAR();
    RD_A(2, 1);          STG(1, pb, tn, 0);  VMC(6);  SBAR(); MM(1); SBAR();
    RD_A(4, 0); RD_B(5); STG(2, pa, tn, 1);           SBAR(); MM(0); SBAR();
    RD_A(4, 1);          STG(3, pb, tn, 1);  VMC(6);  SBAR(); MM(1); SBAR();
    RD_A(6, 0); RD_B(7); STG(4, pa, tn1, 0);          SBAR(); MM(0); SBAR();
    RD_A(6, 1);          STG(5, pb, tn1, 0); VMC(6);  SBAR(); MM(1); SBAR();
  }

  const int rowb = by * 256 + wm * 128 + fq * 4;
  const bool isQ = (bx < 8);
  ushort* dst = isQ ? Qh : Kh;
  const float qscl = isQ ? 0.08838834764831845f : 1.0f;
  #pragma unroll
  for (int mf = 0; mf < 8; mf++)
    #pragma unroll
    for (int nf = 0; nf < 4; nf++){
      int col = bx * 256 + wn * 64 + nf * 16 + fr;
      int cg = col & 2047;
      int hh = cg >> 7, dd = cg & 127, jj = (cg >> 1) & 63;
      #pragma unroll
      for (int i = 0; i < 4; i++){
        int row = rowb + mf * 16 + i;
        int s = row & (S_LEN - 1), bb = row >> 11;
        float2 c2 = cs[s * 64 + jj];
        float v = acc[mf][nf][i];
        float p = __shfl_xor(v, 1);
        float o = (fr & 1) ? fmaf(p, c2.y, v * c2.x) : fmaf(v, c2.x, -p * c2.y);
        dst[((size_t)(bb * NH + hh) * S_LEN + s) * DK + dd] = f2bf(o * qscl);
      }
    }
}

// ================= 256x128 8-phase skeleton (shared by V GEMM and WO GEMM) =================
#define WSTG_A(si, tks, khh) do{ \
  const ushort* _s = pa + (tks)*64 + (khh)*32; \
  gload16(_s,                  lds + (si)*8192 + wid*512); \
  gload16(_s + (size_t)128*GK, lds + (si)*8192 + 4096 + wid*512); \
}while(0)
#define WSTG_B(si, tks, khh) do{ \
  const ushort* _s = pb + (tks)*64 + (khh)*32; \
  gload16(_s, lds + 32768 + (si)*4096 + wid*512); \
}while(0)
#define WRD_A(si, mhf) do{ \
  af[0] = *reinterpret_cast<const bf16x8*>(ldsc + (si)*16384 + wm*4096 + ((mhf)*2+0)*1024 + frA); \
  af[1] = *reinterpret_cast<const bf16x8*>(ldsc + (si)*16384 + wm*4096 + ((mhf)*2+1)*1024 + frA); \
}while(0)
#define WRD_B(si) do{ \
  bfr[0] = *reinterpret_cast<const bf16x8*>(ldsc + 65536 + (si)*8192 + wn*4096 + 0*1024 + frA); \
  bfr[1] = *reinterpret_cast<const bf16x8*>(ldsc + 65536 + (si)*8192 + wn*4096 + 1*1024 + frA); \
  bfr[2] = *reinterpret_cast<const bf16x8*>(ldsc + 65536 + (si)*8192 + wn*4096 + 2*1024 + frA); \
  bfr[3] = *reinterpret_cast<const bf16x8*>(ldsc + 65536 + (si)*8192 + wn*4096 + 3*1024 + frA); \
}while(0)
#define WMM(mhf) do{ \
  __builtin_amdgcn_s_setprio(1); \
  _Pragma("unroll") \
  for (int k2 = 0; k2 < 2; k2++) \
    _Pragma("unroll") \
    for (int nf = 0; nf < 4; nf++) \
      acc[(mhf)*2+k2][nf] = __builtin_amdgcn_mfma_f32_16x16x32_bf16(af[k2], bfr[nf], acc[(mhf)*2+k2][nf], 0, 0, 0); \
  __builtin_amdgcn_s_setprio(0); \
}while(0)

#define WBODY() \
  WSTG_A(0, 0, 0); WSTG_B(0, 0, 0); WSTG_A(1, 0, 1); WSTG_B(1, 0, 1); \
  WSTG_A(2, 1, 0); WSTG_B(2, 1, 0); \
  VMC(6); \
  SBAR(); \
  _Pragma("unroll 1") \
  for (int it = 0; it < 16; ++it){ \
    const int tb  = 2 * it + 1; \
    const int tn  = (2 * it + 2 < 32) ? 2 * it + 2 : 31; \
    const int tn1 = (2 * it + 3 < 32) ? 2 * it + 3 : 31; \
    WRD_A(0, 0); WRD_B(0); WSTG_A(3, tb, 1);            SBAR(); WMM(0); SBAR(); \
    WRD_A(0, 1);           WSTG_B(3, tb, 1);  VMC(6);   SBAR(); WMM(1); SBAR(); \
    WRD_A(1, 0); WRD_B(1); WSTG_A(0, tn, 0);            SBAR(); WMM(0); SBAR(); \
    WRD_A(1, 1);           WSTG_B(0, tn, 0);  VMC(6);   SBAR(); WMM(1); SBAR(); \
    WRD_A(2, 0); WRD_B(2); WSTG_A(1, tn, 1);            SBAR(); WMM(0); SBAR(); \
    WRD_A(2, 1);           WSTG_B(1, tn, 1);  VMC(6);   SBAR(); WMM(1); SBAR(); \
    WRD_A(3, 0); WRD_B(3); WSTG_A(2, tn1, 0);           SBAR(); WMM(0); SBAR(); \
    WRD_A(3, 1);           WSTG_B(2, tn1, 0); VMC(6);   SBAR(); WMM(1); SBAR(); \
  }

__launch_bounds__(512, 2)
__global__ void k_gemm_v(const ushort* __restrict__ A, const ushort* __restrict__ Bt,
                         ushort* __restrict__ Vt){
  __shared__ short lds[49152];   // 96 KiB
  const int tid = threadIdx.x, lane = tid & 63, wid = tid >> 6;
  const int wm = wid >> 1, wn = wid & 1;
  const int fr = lane & 15, fq = lane >> 4;

  const int bid = blockIdx.x;
  const int b2 = (bid & 7) * 32 + (bid >> 3);
  const int by = b2 >> 4, bx = b2 & 15;

  const int rbase = wid * 16 + (lane >> 2);
  const int kup = ((lane & 3) ^ ((lane >> 3) & 3)) * 8;
  const ushort* pa = A  + (size_t)(by * 256 + rbase) * GK + kup;
  const ushort* pb = Bt + (size_t)(bx * 128 + rbase) * GK + kup;

  const char* ldsc = (const char*)lds;
  const int frA = fr * 64 + ((fq * 16) ^ (((fr >> 1) & 3) << 4));

  f32x4 acc[4][4] = {};
  bf16x8 af[2], bfr[4];

  WBODY();

  const int rowb = by * 256 + wm * 64 + fq * 4;
  #pragma unroll
  for (int mf = 0; mf < 4; mf++){
    int row0 = rowb + mf * 16;
    int s0 = row0 & (S_LEN - 1), bb = row0 >> 11;
    #pragma unroll
    for (int nf = 0; nf < 4; nf++){
      int col = bx * 128 + wn * 64 + nf * 16 + fr;
      int hh = col >> 7, dd = col & 127;
      ushort4 o;
      o.x = f2bf(acc[mf][nf][0]); o.y = f2bf(acc[mf][nf][1]);
      o.z = f2bf(acc[mf][nf][2]); o.w = f2bf(acc[mf][nf][3]);
      *reinterpret_cast<ushort4*>(&Vt[((size_t)(bb * NH + hh) * DK + dd) * S_LEN + s0]) = o;
    }
  }
}

__launch_bounds__(512, 2)
__global__ void k_gemm_wo(const ushort* __restrict__ A, const ushort* __restrict__ Bt,
                          float* __restrict__ C){
  __shared__ short lds[49152];   // 96 KiB
  const int tid = threadIdx.x, lane = tid & 63, wid = tid >> 6;
  const int wm = wid >> 1, wn = wid & 1;
  const int fr = lane & 15, fq = lane >> 4;

  const int bid = blockIdx.x;
  const int b2 = (bid & 7) * 32 + (bid >> 3);
  const int by = b2 >> 4, bx = b2 & 15;

  const int rbase = wid * 16 + (lane >> 2);
  const int kup = ((lane & 3) ^ ((lane >> 3) & 3)) * 8;
  const ushort* pa = A  + (size_t)(by * 256 + rbase) * GK + kup;
  const ushort* pb = Bt + (size_t)(bx * 128 + rbase) * GK + kup;

  const char* ldsc = (const char*)lds;
  const int frA = fr * 64 + ((fq * 16) ^ (((fr >> 1) & 3) << 4));

  f32x4 acc[4][4] = {};
  bf16x8 af[2], bfr[4];

  WBODY();

  const int orow = by * 256 + wm * 64 + fq * 4;
  const int ocol = bx * 128 + wn * 64 + fr;
  #pragma unroll
  for (int mf = 0; mf < 4; mf++)
    #pragma unroll
    for (int nf = 0; nf < 4; nf++)
      #pragma unroll
      for (int i = 0; i < 4; i++)
        C[(size_t)(orow + mf * 16 + i) * DM + ocol + nf * 16] = acc[mf][nf][i];
}

// ---------------- causal flash attention: 32x32 MFMA, pipelined, in-block pairing ----------------
// 256 blocks x 512 thr (8 waves x 32 q-rows = 256-row chunk), 1 block/CU, LDS 64KB.
// Block pid runs chunk j=7-pid then j=pid: work = (4(7-pid)+4)+(4pid+4) = 36 tiles, uniform
// (r13/14's 512-single-chunk grid left half the machine idle -- Occupancy 13%).
// Wave-uniform guard: skip QK/SMPV for tiles t > Wlim=(qrb+31)>>6 (fully masked).
// Pipeline per iter: STK(t+1) | QK(t) | SM+PV(t-1) | barrier | STV(t+1)  (r14 discipline).
#define STK(tt) do{ char* _kd = (char*)Kt + ((tt) & 1) * 16384; \
  _Pragma("unroll") for (int jj = 0; jj < 2; jj++){ \
    int ins = wid * 2 + jj; \
    gload16(kbp + (size_t)((tt) * 64 + kro[jj]) * DK + kco[jj], _kd + ins * 1024); } }while(0)

#define STV(tt) do{ char* _vd = (char*)Vl + ((tt) & 1) * 16384; \
  _Pragma("unroll") for (int jj = 0; jj < 2; jj++){ \
    int ins = wid * 2 + jj; \
    gload16(vbp + (size_t)vro[jj] * S_LEN + (tt) * 64 + vco[jj], _vd + ins * 1024); } }while(0)

#define QKS(SC, tt) do{ \
  const char* _KtB = (const char*)Kt + ((tt) & 1) * 16384; \
  f32x16 _z = {}; SC[0] = _z; SC[1] = _z; \
  _Pragma("unroll") for (int s = 0; s < 8; s++){ \
    bf16x8 kf0 = *reinterpret_cast<const bf16x8*>(_KtB + ql * 256 + ((s*32 + h*16) ^ swz)); \
    bf16x8 kf1 = *reinterpret_cast<const bf16x8*>(_KtB + (32 + ql) * 256 + ((s*32 + h*16) ^ swz)); \
    SC[0] = __builtin_amdgcn_mfma_f32_32x32x16_bf16(kf0, qf[s], SC[0], 0, 0, 0); \
    SC[1] = __builtin_amdgcn_mfma_f32_32x32x16_bf16(kf1, qf[s], SC[1], 0, 0, 0); \
  } }while(0)

#define SMPV(SC, tt) do{ \
  const int _k0 = (tt) * 64; \
  const char* _VlB = (const char*)Vl + ((tt) & 1) * 16384; \
  if (_k0 + 63 > qrb){ \
    _Pragma("unroll") for (int kb = 0; kb < 2; kb++) \
      _Pragma("unroll") for (int r = 0; r < 16; r++) \
        if (_k0 + kb * 32 + (r & 3) + 8 * (r >> 2) + 4 * h > qrow) SC[kb][r] = -1e30f; \
  } \
  float mx = SC[0][0]; \
  _Pragma("unroll") for (int kb = 0; kb < 2; kb++) \
    _Pragma("unroll") for (int r = 0; r < 16; r++) mx = fmaxf(mx, SC[kb][r]); \
  mx = fmaxf(mx, __shfl_xor(mx, 32)); \
  if (!__all(mx <= mi + 8.0f)){ \
    float mn = fmaxf(mi, mx); \
    float scl = __expf(mi - mn); \
    mi = mn; li *= scl; \
    float sclr[16]; \
    _Pragma("unroll") for (int r = 0; r < 16; r++) sclr[r] = __shfl(scl, (r & 3) + 8 * (r >> 2) + 4 * h); \
    _Pragma("unroll") for (int dt = 0; dt < 4; dt++) \
      _Pragma("unroll") for (int r = 0; r < 16; r++) accO[dt][r] *= sclr[r]; \
  } \
  float rs = 0.f; \
  _Pragma("unroll") for (int kb = 0; kb < 2; kb++) \
    _Pragma("unroll") for (int r = 0; r < 16; r++){ \
      float e = __expf(SC[kb][r] - mi); SC[kb][r] = e; rs += e; } \
  rs += __shfl_xor(rs, 32); \
  li += rs; \
  bf16x8 pf[4]; \
  _Pragma("unroll") for (int t2 = 0; t2 < 4; t2++){ \
    const int kbb = t2 >> 1, rb = (t2 & 1) * 8; \
    u32 wA0 = cvtpk(SC[kbb][rb + 0], SC[kbb][rb + 1]); \
    u32 wA1 = cvtpk(SC[kbb][rb + 2], SC[kbb][rb + 3]); \
    u32 wB0 = cvtpk(SC[kbb][rb + 4], SC[kbb][rb + 5]); \
    u32 wB1 = cvtpk(SC[kbb][rb + 6], SC[kbb][rb + 7]); \
    u32 X = h ? wA0 : wB0; \
    u32 Y = h ? wA1 : wB1; \
    u32 x0 = (u32)__shfl_xor((int)X, 32); \
    u32 x1 = (u32)__shfl_xor((int)Y, 32); \
    u32 fw[4]; \
    fw[0] = h ? x0 : wA0; fw[1] = h ? x1 : wA1; \
    fw[2] = h ? wB0 : x0; fw[3] = h ? wB1 : x1; \
    __builtin_memcpy(&pf[t2], fw, 16); \
  } \
  _Pragma("unroll") for (int dt = 0; dt < 4; dt++){ \
    const int vrow = dt * 32 + ql; \
    const int vswz = (vrow & 7) << 4; \
    _Pragma("unroll") for (int t2 = 0; t2 < 4; t2++){ \
      bf16x8 vf = *reinterpret_cast<const bf16x8*>(_VlB + vrow * 128 + ((t2 * 32 + h * 16) ^ vswz)); \
      accO[dt] = __builtin_amdgcn_mfma_f32_32x32x16_bf16(pf[t2], vf, accO[dt], 0, 0, 0); \
    } \
  } }while(0)

__launch_bounds__(512, 2)
__global__ void k_attn(const ushort* __restrict__ Q, const ushort* __restrict__ K,
                       const ushort* __restrict__ Vt, ushort* __restrict__ O){
  __shared__ short Kt[2][64 * 128];   // [kv][d] swizzled (16KB each)
  __shared__ short Vl[2][128 * 64];   // [d][kv] swizzled (16KB each)
  const int tid = threadIdx.x, lane = tid & 63, wid = tid >> 6;
  const int bid = blockIdx.x;
  const int bh = bid & 31, b = bh >> 4, hh = bh & 15;
  const int pid = bid >> 5;                    // 0..7
  const int ql = lane & 31, h = lane >> 5;
  const int swz = (ql & 7) << 4;

  const ushort* kbp = K  + (size_t)bh * S_LEN * DK;
  const ushort* vbp = Vt + (size_t)bh * DK * S_LEN;
  ushort* ob = O + (size_t)b * S_LEN * DM;

  int kro[2], kco[2], vro[2], vco[2];
  #pragma unroll
  for (int jj = 0; jj < 2; jj++){
    int ins = wid * 2 + jj;
    kro[jj] = ins * 4 + (lane >> 4);
    kco[jj] = 8 * ((lane & 15) ^ (kro[jj] & 7));
    vro[jj] = ins * 8 + (lane >> 3);
    vco[jj] = 8 * ((lane & 7) ^ (vro[jj] & 7));
  }

  #pragma unroll 1
  for (int half = 0; half < 2; half++){
    const int j = half ? pid : 7 - pid;
    const int nt = 4 * j + 4;                  // even, >= 4
    const int qrb = j * 256 + wid * 32;
    const int qrow = qrb + ql;
    const int Wlim = (qrb + 31) >> 6;          // last tile this wave needs

    bf16x8 qf[8];
    #pragma unroll
    for (int s = 0; s < 8; s++)
      qf[s] = *reinterpret_cast<const bf16x8*>(
          Q + ((size_t)bh * S_LEN + qrow) * DK + s * 16 + h * 8);

    float mi = -1e30f, li = 0.f;
    f32x16 accO[4] = {};
    f32x16 scA[2], scB[2];

    // prologue (barrier also isolates previous half's readers from restaging)
    __syncthreads();
    STK(0); STV(0);
    __syncthreads();
    STK(1);
    QKS(scA, 0);
    __syncthreads();
    STV(1);

    int t = 1;
    #pragma unroll 1
    for (; t + 1 < nt; t += 2){
      STK(t + 1);
      if (t <= Wlim) QKS(scB, t);
      SMPV(scA, t - 1);
      __syncthreads();
      STV(t + 1);
      STK(t + 2);
      if (t + 1 <= Wlim) QKS(scA, t + 1);
      if (t <= Wlim) SMPV(scB, t);
      __syncthreads();
      STV(t + 2);
    }
    // tail: t == nt-1
    if (t <= Wlim) QKS(scB, t);
    if (t - 1 <= Wlim) SMPV(scA, t - 1);
    __syncthreads();          // drains STV(nt-1)
    if (t <= Wlim) SMPV(scB, t);

    float invr[16];
    #pragma unroll
    for (int r = 0; r < 16; r++) invr[r] = 1.f / __shfl(li, (r & 3) + 8 * (r >> 2) + 4 * h);
    #pragma unroll
    for (int dt = 0; dt < 4; dt++)
      #pragma unroll
      for (int r = 0; r < 16; r++){
        int row = qrb + (r & 3) + 8 * (r >> 2) + 4 * h;
        ob[(size_t)row * DM + hh * DK + dt * 32 + ql] = f2bf(accO[dt][r] * invr[r]);
      }
  }
}

extern "C" void kernel_launch(void* const* d_in, const int* in_sizes, int n_in,
                              void* d_out, int out_size, void* d_ws, size_t ws_size,
                              hipStream_t stream){
  const float* x  = (const float*)d_in[0];
  const float* wq = (const float*)d_in[1];
  const float* wk = (const float*)d_in[2];
  const float* wv = (const float*)d_in[3];
  const float* wo = (const float*)d_in[4];
  const int* pos  = (const int*)d_in[5];
  float* out = (float*)d_out;

  char* ws = (char*)d_ws;
  ushort* xb   = (ushort*)(ws);               // 16 MiB; Ob aliases after GEMMs consume xb
  ushort* Ob   = xb;
  ushort* wqkv = (ushort*)(ws + 16777216);    // 24 MiB
  ushort* Qh   = (ushort*)(ws + 41943040);    // 16 MiB
  ushort* Kh   = (ushort*)(ws + 58720256);    // 16 MiB
  ushort* Vt   = (ushort*)(ws + 75497472);    // 16 MiB
  float2* cs   = (float2*)(ws + 92274688);    // 1 MiB
  ushort* wob  = (ushort*)(ws + 93323264);    // 8 MiB

  k_rope_table<<<(S_LEN * 64) / 256, 256, 0, stream>>>(pos, cs);
  k_conv<<<24576, 256, 0, stream>>>(x, wq, wk, wv, wo, xb, wqkv, wob);

  k_gemm_qk<<<256, 512, 0, stream>>>(xb, wqkv, cs, Qh, Kh);
  k_gemm_v<<<256, 512, 0, stream>>>(xb, wqkv + (size_t)2 * DM * DM, Vt);

  k_attn<<<256, 512, 0, stream>>>(Qh, Kh, Vt, Ob);

  k_gemm_wo<<<256, 512, 0, stream>>>(Ob, wob, out);
}

// Round 16
// 243.368 us; speedup vs baseline: 1.1448x; 1.1448x over previous
//
#include <hip/hip_runtime.h>

#define S_LEN 2048
#define DM 2048
#define NH 16
#define DK 128
#define BB 2
#define BH (BB*NH)
#define GK 2048

typedef float f32x4 __attribute__((ext_vector_type(4)));
typedef __bf16 bf16x8 __attribute__((ext_vector_type(8)));
typedef __bf16 bf16x4 __attribute__((ext_vector_type(4)));
typedef unsigned int u32;

#define AS1 __attribute__((address_space(1)))
#define AS3 __attribute__((address_space(3)))

__device__ inline void gload16(const void* g, void* l){
  __builtin_amdgcn_global_load_lds((AS1 const u32*)g, (AS3 u32*)l, 16, 0, 0);
}

__device__ inline ushort f2bf(float f){
  __bf16 h = (__bf16)f;
  ushort u;
  __builtin_memcpy(&u, &h, 2);
  return u;
}

// ---------------- all fp32->bf16 conversions (x + 4 weights) in one launch ----------------
__global__ void k_conv(const float* __restrict__ x, const float* __restrict__ wq,
                       const float* __restrict__ wk, const float* __restrict__ wv,
                       const float* __restrict__ wo4,
                       ushort* __restrict__ xb, ushort* __restrict__ dqkv,
                       ushort* __restrict__ dwo){
  int i = blockIdx.x * 256 + threadIdx.x;    // 0 .. 6M-1 (float4 units)
  int sel = i >> 20;
  int off = i & ((1 << 20) - 1);
  const float* s; ushort* d;
  if (sel < 2){ s = x + ((size_t)sel << 22); d = xb + ((size_t)sel << 22); }
  else if (sel == 2){ s = wq; d = dqkv; }
  else if (sel == 3){ s = wk; d = dqkv + (size_t)DM * DM; }
  else if (sel == 4){ s = wv; d = dqkv + (size_t)2 * DM * DM; }
  else { s = wo4; d = dwo; }
  float4 v = reinterpret_cast<const float4*>(s)[off];
  ushort4 o;
  o.x = f2bf(v.x); o.y = f2bf(v.y); o.z = f2bf(v.z); o.w = f2bf(v.w);
  reinterpret_cast<ushort4*>(d)[off] = o;
}

// ---------------- rope cos/sin table [S][64] as float2 {cos,sin} ----------------
__global__ void k_rope_table(const int* __restrict__ pos, float2* __restrict__ cs){
  int idx = blockIdx.x * 256 + threadIdx.x;
  if (idx >= S_LEN * 64) return;
  int s = idx >> 6, i = idx & 63;
  float inv = expf(-0.14391156831212787f * (float)i);   // 10000^(-i/64)
  float f = (float)pos[s] * inv;
  cs[idx] = make_float2(cosf(f), sinf(f));
}

#define SBAR() do{ __builtin_amdgcn_s_barrier(); __builtin_amdgcn_sched_barrier(0); }while(0)
#define VMC(n) asm volatile("s_waitcnt vmcnt(" #n ")" ::: "memory")

// ================= Q+K GEMM: 256x256 tile, BK=64, 8 waves, 8-phase =================
#define STG(slot, srcp, tks, khh) do{ \
  const ushort* _s = (srcp) + (tks)*64 + (khh)*32; \
  gload16(_s,                    lds + (slot)*8192 + wid*512); \
  gload16(_s + (size_t)128*GK,   lds + (slot)*8192 + 4096 + wid*512); \
}while(0)

#define RD_A(slot, mh) do{ \
  af[0] = *reinterpret_cast<const bf16x8*>(ldsc + (slot)*16384 + wm*8192 + ((mh)*4+0)*1024 + frA); \
  af[1] = *reinterpret_cast<const bf16x8*>(ldsc + (slot)*16384 + wm*8192 + ((mh)*4+1)*1024 + frA); \
  af[2] = *reinterpret_cast<const bf16x8*>(ldsc + (slot)*16384 + wm*8192 + ((mh)*4+2)*1024 + frA); \
  af[3] = *reinterpret_cast<const bf16x8*>(ldsc + (slot)*16384 + wm*8192 + ((mh)*4+3)*1024 + frA); \
}while(0)

#define RD_B(slot) do{ \
  bfr[0] = *reinterpret_cast<const bf16x8*>(ldsc + (slot)*16384 + wn*4096 + 0*1024 + frA); \
  bfr[1] = *reinterpret_cast<const bf16x8*>(ldsc + (slot)*16384 + wn*4096 + 1*1024 + frA); \
  bfr[2] = *reinterpret_cast<const bf16x8*>(ldsc + (slot)*16384 + wn*4096 + 2*1024 + frA); \
  bfr[3] = *reinterpret_cast<const bf16x8*>(ldsc + (slot)*16384 + wn*4096 + 3*1024 + frA); \
}while(0)

#define MM(mh) do{ \
  __builtin_amdgcn_s_setprio(1); \
  _Pragma("unroll") \
  for (int mf2 = 0; mf2 < 4; mf2++) \
    _Pragma("unroll") \
    for (int nf = 0; nf < 4; nf++) \
      acc[(mh)*4+mf2][nf] = __builtin_amdgcn_mfma_f32_16x16x32_bf16(af[mf2], bfr[nf], acc[(mh)*4+mf2][nf], 0, 0, 0); \
  __builtin_amdgcn_s_setprio(0); \
}while(0)

__launch_bounds__(512, 2)
__global__ void k_gemm_qk(const ushort* __restrict__ A, const ushort* __restrict__ Bt,
                          const float2* __restrict__ cs,
                          ushort* __restrict__ Qh, ushort* __restrict__ Kh){
  __shared__ short lds[65536];   // 128 KiB: 8 half-slots x 16 KB
  const int tid = threadIdx.x, lane = tid & 63, wid = tid >> 6;
  const int wm = wid >> 2, wn = wid & 3;
  const int fr = lane & 15, fq = lane >> 4;

  const int bid = blockIdx.x;                  // 256 = 8*32, bijective XCD swizzle
  const int b2 = (bid & 7) * 32 + (bid >> 3);
  const int by = b2 >> 4, bx = b2 & 15;

  const int rbase = wid * 16 + (lane >> 2);
  const int kup = ((lane & 3) ^ ((lane >> 3) & 3)) * 8;
  const ushort* pa = A  + (size_t)(by * 256 + rbase) * GK + kup;
  const ushort* pb = Bt + (size_t)(bx * 256 + rbase) * GK + kup;

  const char* ldsc = (const char*)lds;
  const int frA = fr * 64 + ((fq * 16) ^ (((fr >> 1) & 3) << 4));

  f32x4 acc[8][4] = {};
  bf16x8 af[4], bfr[4];

  STG(0, pa, 0, 0); STG(1, pb, 0, 0); STG(2, pa, 0, 1); STG(3, pb, 0, 1);
  STG(4, pa, 1, 0); STG(5, pb, 1, 0);
  VMC(8);
  SBAR();

  #pragma unroll 1
  for (int it = 0; it < 16; ++it){
    const int tb  = 2 * it + 1;
    const int tn  = (2 * it + 2 < 32) ? 2 * it + 2 : 31;
    const int tn1 = (2 * it + 3 < 32) ? 2 * it + 3 : 31;
    RD_A(0, 0); RD_B(1); STG(6, pa, tb, 1);           SBAR(); MM(0); SBAR();
    RD_A(0, 1);          STG(7, pb, tb, 1);  VMC(6);  SBAR(); MM(1); SBAR();
    RD_A(2, 0); RD_B(3); STG(0, pa, tn, 0);           SBAR(); MM(0); SBAR();
    RD_A(2, 1);          STG(1, pb, tn, 0);  VMC(6);  SBAR(); MM(1); SBAR();
    RD_A(4, 0); RD_B(5); STG(2, pa, tn, 1);           SBAR(); MM(0); SBAR();
    RD_A(4, 1);          STG(3, pb, tn, 1);  VMC(6);  SBAR(); MM(1); SBAR();
    RD_A(6, 0); RD_B(7); STG(4, pa, tn1, 0);          SBAR(); MM(0); SBAR();
    RD_A(6, 1);          STG(5, pb, tn1, 0); VMC(6);  SBAR(); MM(1); SBAR();
  }

  const int rowb = by * 256 + wm * 128 + fq * 4;
  const bool isQ = (bx < 8);
  ushort* dst = isQ ? Qh : Kh;
  const float qscl = isQ ? 0.08838834764831845f : 1.0f;
  #pragma unroll
  for (int mf = 0; mf < 8; mf++)
    #pragma unroll
    for (int nf = 0; nf < 4; nf++){
      int col = bx * 256 + wn * 64 + nf * 16 + fr;
      int cg = col & 2047;
      int hh = cg >> 7, dd = cg & 127, jj = (cg >> 1) & 63;
      #pragma unroll
      for (int i = 0; i < 4; i++){
        int row = rowb + mf * 16 + i;
        int s = row & (S_LEN - 1), bb = row >> 11;
        float2 c2 = cs[s * 64 + jj];
        float v = acc[mf][nf][i];
        float p = __shfl_xor(v, 1);
        float o = (fr & 1) ? fmaf(p, c2.y, v * c2.x) : fmaf(v, c2.x, -p * c2.y);
        dst[((size_t)(bb * NH + hh) * S_LEN + s) * DK + dd] = f2bf(o * qscl);
      }
    }
}

// ================= 256x128 8-phase skeleton (shared by V GEMM and WO GEMM) =================
#define WSTG_A(si, tks, khh) do{ \
  const ushort* _s = pa + (tks)*64 + (khh)*32; \
  gload16(_s,                  lds + (si)*8192 + wid*512); \
  gload16(_s + (size_t)128*GK, lds + (si)*8192 + 4096 + wid*512); \
}while(0)
#define WSTG_B(si, tks, khh) do{ \
  const ushort* _s = pb + (tks)*64 + (khh)*32; \
  gload16(_s, lds + 32768 + (si)*4096 + wid*512); \
}while(0)
#define WRD_A(si, mhf) do{ \
  af[0] = *reinterpret_cast<const bf16x8*>(ldsc + (si)*16384 + wm*4096 + ((mhf)*2+0)*1024 + frA); \
  af[1] = *reinterpret_cast<const bf16x8*>(ldsc + (si)*16384 + wm*4096 + ((mhf)*2+1)*1024 + frA); \
}while(0)
#define WRD_B(si) do{ \
  bfr[0] = *reinterpret_cast<const bf16x8*>(ldsc + 65536 + (si)*8192 + wn*4096 + 0*1024 + frA); \
  bfr[1] = *reinterpret_cast<const bf16x8*>(ldsc + 65536 + (si)*8192 + wn*4096 + 1*1024 + frA); \
  bfr[2] = *reinterpret_cast<const bf16x8*>(ldsc + 65536 + (si)*8192 + wn*4096 + 2*1024 + frA); \
  bfr[3] = *reinterpret_cast<const bf16x8*>(ldsc + 65536 + (si)*8192 + wn*4096 + 3*1024 + frA); \
}while(0)
#define WMM(mhf) do{ \
  __builtin_amdgcn_s_setprio(1); \
  _Pragma("unroll") \
  for (int k2 = 0; k2 < 2; k2++) \
    _Pragma("unroll") \
    for (int nf = 0; nf < 4; nf++) \
      acc[(mhf)*2+k2][nf] = __builtin_amdgcn_mfma_f32_16x16x32_bf16(af[k2], bfr[nf], acc[(mhf)*2+k2][nf], 0, 0, 0); \
  __builtin_amdgcn_s_setprio(0); \
}while(0)

#define WBODY() \
  WSTG_A(0, 0, 0); WSTG_B(0, 0, 0); WSTG_A(1, 0, 1); WSTG_B(1, 0, 1); \
  WSTG_A(2, 1, 0); WSTG_B(2, 1, 0); \
  VMC(6); \
  SBAR(); \
  _Pragma("unroll 1") \
  for (int it = 0; it < 16; ++it){ \
    const int tb  = 2 * it + 1; \
    const int tn  = (2 * it + 2 < 32) ? 2 * it + 2 : 31; \
    const int tn1 = (2 * it + 3 < 32) ? 2 * it + 3 : 31; \
    WRD_A(0, 0); WRD_B(0); WSTG_A(3, tb, 1);            SBAR(); WMM(0); SBAR(); \
    WRD_A(0, 1);           WSTG_B(3, tb, 1);  VMC(6);   SBAR(); WMM(1); SBAR(); \
    WRD_A(1, 0); WRD_B(1); WSTG_A(0, tn, 0);            SBAR(); WMM(0); SBAR(); \
    WRD_A(1, 1);           WSTG_B(0, tn, 0);  VMC(6);   SBAR(); WMM(1); SBAR(); \
    WRD_A(2, 0); WRD_B(2); WSTG_A(1, tn, 1);            SBAR(); WMM(0); SBAR(); \
    WRD_A(2, 1);           WSTG_B(1, tn, 1);  VMC(6);   SBAR(); WMM(1); SBAR(); \
    WRD_A(3, 0); WRD_B(3); WSTG_A(2, tn1, 0);           SBAR(); WMM(0); SBAR(); \
    WRD_A(3, 1);           WSTG_B(2, tn1, 0); VMC(6);   SBAR(); WMM(1); SBAR(); \
  }

__launch_bounds__(512, 2)
__global__ void k_gemm_v(const ushort* __restrict__ A, const ushort* __restrict__ Bt,
                         ushort* __restrict__ Vt){
  __shared__ short lds[49152];   // 96 KiB
  const int tid = threadIdx.x, lane = tid & 63, wid = tid >> 6;
  const int wm = wid >> 1, wn = wid & 1;
  const int fr = lane & 15, fq = lane >> 4;

  const int bid = blockIdx.x;
  const int b2 = (bid & 7) * 32 + (bid >> 3);
  const int by = b2 >> 4, bx = b2 & 15;

  const int rbase = wid * 16 + (lane >> 2);
  const int kup = ((lane & 3) ^ ((lane >> 3) & 3)) * 8;
  const ushort* pa = A  + (size_t)(by * 256 + rbase) * GK + kup;
  const ushort* pb = Bt + (size_t)(bx * 128 + rbase) * GK + kup;

  const char* ldsc = (const char*)lds;
  const int frA = fr * 64 + ((fq * 16) ^ (((fr >> 1) & 3) << 4));

  f32x4 acc[4][4] = {};
  bf16x8 af[2], bfr[4];

  WBODY();

  const int rowb = by * 256 + wm * 64 + fq * 4;
  #pragma unroll
  for (int mf = 0; mf < 4; mf++){
    int row0 = rowb + mf * 16;
    int s0 = row0 & (S_LEN - 1), bb = row0 >> 11;
    #pragma unroll
    for (int nf = 0; nf < 4; nf++){
      int col = bx * 128 + wn * 64 + nf * 16 + fr;
      int hh = col >> 7, dd = col & 127;
      ushort4 o;
      o.x = f2bf(acc[mf][nf][0]); o.y = f2bf(acc[mf][nf][1]);
      o.z = f2bf(acc[mf][nf][2]); o.w = f2bf(acc[mf][nf][3]);
      *reinterpret_cast<ushort4*>(&Vt[((size_t)(bb * NH + hh) * DK + dd) * S_LEN + s0]) = o;
    }
  }
}

__launch_bounds__(512, 2)
__global__ void k_gemm_wo(const ushort* __restrict__ A, const ushort* __restrict__ Bt,
                          float* __restrict__ C){
  __shared__ short lds[49152];   // 96 KiB
  const int tid = threadIdx.x, lane = tid & 63, wid = tid >> 6;
  const int wm = wid >> 1, wn = wid & 1;
  const int fr = lane & 15, fq = lane >> 4;

  const int bid = blockIdx.x;
  const int b2 = (bid & 7) * 32 + (bid >> 3);
  const int by = b2 >> 4, bx = b2 & 15;

  const int rbase = wid * 16 + (lane >> 2);
  const int kup = ((lane & 3) ^ ((lane >> 3) & 3)) * 8;
  const ushort* pa = A  + (size_t)(by * 256 + rbase) * GK + kup;
  const ushort* pb = Bt + (size_t)(bx * 128 + rbase) * GK + kup;

  const char* ldsc = (const char*)lds;
  const int frA = fr * 64 + ((fq * 16) ^ (((fr >> 1) & 3) << 4));

  f32x4 acc[4][4] = {};
  bf16x8 af[2], bfr[4];

  WBODY();

  const int orow = by * 256 + wm * 64 + fq * 4;
  const int ocol = bx * 128 + wn * 64 + fr;
  #pragma unroll
  for (int mf = 0; mf < 4; mf++)
    #pragma unroll
    for (int nf = 0; nf < 4; nf++)
      #pragma unroll
      for (int i = 0; i < 4; i++)
        C[(size_t)(orow + mf * 16 + i) * DM + ocol + nf * 16] = acc[mf][nf][i];
}

// ---------------- causal flash attention: 4 waves x 16 q-rows, 64-row paired chunks ----------------
// 512 blocks x 256 thr, 2 blocks/CU (LDS 74KB, VGPR ~88) -> 8 waves/CU SUSTAINED.
// 32 chunks/bh (64 rows); block pid in [0,16) runs j=31-pid then j=pid: work = 33 tiles uniform.
// (r15 bug: 256-row chunks gave only 8 chunks, pairing double-covered -> 2x work. Fixed here.)
// Inner loop = r12's verified swapped-QK 16x16 kernel (prescaled Q, defer-max, reg softmax,
// P via per-wave LDS 160B-stride). Two independent 4-wave blocks per CU overlap phases (m114).
__launch_bounds__(256, 2)
__global__ void k_attn(const ushort* __restrict__ Q, const ushort* __restrict__ K,
                       const ushort* __restrict__ Vt, ushort* __restrict__ O){
  __shared__ short Kt[2][64 * 128];   // [kv][d] swizzled (16KB each)
  __shared__ short Vl[2][128 * 64];   // [d][kv] swizzled (16KB each)
  __shared__ short Pl[4][16 * 80];    // per-wave P, 160B row stride (2.5KB each)
  const int tid = threadIdx.x, lane = tid & 63, wid = tid >> 6;
  const int bid = blockIdx.x;
  const int pid = bid >> 5;           // 0..15
  const int bh = bid & 31;
  const int b = bh >> 4, h = bh & 15;
  const int fr = lane & 15, fq = lane >> 4;
  const int swz = (fr & 7) << 4;

  const ushort* kb = K  + (size_t)bh * S_LEN * DK;
  const ushort* vb = Vt + (size_t)bh * DK * S_LEN;
  char* PlB = (char*)Pl + wid * 2560;
  ushort* ob = O + (size_t)b * S_LEN * DM;

  // staging: 4 waves x 4 instrs for K and V (16KB tile each)
  int kro[4], kco[4], vro[4], vco[4];
  #pragma unroll
  for (int jj = 0; jj < 4; jj++){
    int ins = wid * 4 + jj;
    kro[jj] = ins * 4 + (lane >> 4);
    kco[jj] = 8 * ((lane & 15) ^ (kro[jj] & 7));
    vro[jj] = ins * 8 + (lane >> 3);
    vco[jj] = 8 * ((lane & 7) ^ (vro[jj] & 7));
  }

  #pragma unroll 1
  for (int half = 0; half < 2; half++){
    const int j = half ? pid : 31 - pid;      // 64-row chunk index, 0..31
    const int qr = j * 64 + wid * 16;
    const int nt = j + 1;                     // kv tiles of 64

    bf16x8 qf[4];
    #pragma unroll
    for (int c = 0; c < 4; c++)
      qf[c] = *reinterpret_cast<const bf16x8*>(
          Q + ((size_t)bh * S_LEN + qr + fr) * DK + c * 32 + fq * 8);

    float mi = -1e30f, li = 0.f;     // per-lane scalars: q-row = qr + fr
    f32x4 accO[8] = {};

    __syncthreads();                  // protect buffers from previous half's readers
    {
      char* kd = (char*)Kt;
      char* vd = (char*)Vl;
      #pragma unroll
      for (int jj = 0; jj < 4; jj++){
        int ins = wid * 4 + jj;
        gload16(kb + (size_t)kro[jj] * DK + kco[jj],      kd + ins * 1024);
        gload16(vb + (size_t)vro[jj] * S_LEN + vco[jj],   vd + ins * 1024);
      }
    }
    __syncthreads();

    #pragma unroll 1
    for (int kt = 0; kt < nt; kt++){
      const int k0 = kt * 64;
      const int cur = kt & 1;
      if (kt + 1 < nt){
        const int k1 = k0 + 64;
        char* kd = (char*)Kt + (cur ^ 1) * 16384;
        char* vd = (char*)Vl + (cur ^ 1) * 16384;
        #pragma unroll
        for (int jj = 0; jj < 4; jj++){
          int ins = wid * 4 + jj;
          gload16(kb + (size_t)(k1 + kro[jj]) * DK + kco[jj],  kd + ins * 1024);
          gload16(vb + (size_t)vro[jj] * S_LEN + k1 + vco[jj], vd + ins * 1024);
        }
      }
      const char* KtB = (const char*)Kt + cur * 16384;
      const char* VlB = (const char*)Vl + cur * 16384;

      // ---- swapped QK^T (Q pre-scaled): lane owns q=fr, kv=16ch+4fq+i ----
      f32x4 sc[4] = {};
      #pragma unroll
      for (int c = 0; c < 4; c++){
        bf16x8 kf[4];
        #pragma unroll
        for (int ch = 0; ch < 4; ch++)
          kf[ch] = *reinterpret_cast<const bf16x8*>(
              KtB + (ch * 16 + fr) * 256 + ((c * 64 + fq * 16) ^ swz));
        #pragma unroll
        for (int ch = 0; ch < 4; ch++)
          sc[ch] = __builtin_amdgcn_mfma_f32_16x16x32_bf16(kf[ch], qf[c], sc[ch], 0, 0, 0);
      }

      // ---- causal mask on last tile (kv = k0+16ch+4fq+i vs q = qr+fr) ----
      const int qrow = qr + fr;
      if (kt == nt - 1){
        #pragma unroll
        for (int ch = 0; ch < 4; ch++)
          #pragma unroll
          for (int i = 0; i < 4; i++)
            if (k0 + ch * 16 + fq * 4 + i > qrow) sc[ch][i] = -1e30f;
      }

      // ---- in-register row max + 2 shfl ----
      float mx = sc[0][0];
      #pragma unroll
      for (int ch = 0; ch < 4; ch++)
        #pragma unroll
        for (int i = 0; i < 4; i++) mx = fmaxf(mx, sc[ch][i]);
      mx = fmaxf(mx, __shfl_xor(mx, 16));
      mx = fmaxf(mx, __shfl_xor(mx, 32));

      // ---- T13 defer-max ----
      if (!__all(mx <= mi + 8.0f)){
        float mn = fmaxf(mi, mx);
        float scl = __expf(mi - mn);
        mi = mn;
        li *= scl;
        float sclq[4];
        #pragma unroll
        for (int i = 0; i < 4; i++) sclq[i] = __shfl(scl, fq * 4 + i);
        #pragma unroll
        for (int dt = 0; dt < 8; dt++)
          #pragma unroll
          for (int i = 0; i < 4; i++) accO[dt][i] *= sclq[i];
      }

      float rs = 0.f;
      #pragma unroll
      for (int ch = 0; ch < 4; ch++)
        #pragma unroll
        for (int i = 0; i < 4; i++){
          float e = __expf(sc[ch][i] - mi);
          sc[ch][i] = e;
          rs += e;
        }
      rs += __shfl_xor(rs, 16);
      rs += __shfl_xor(rs, 32);
      li += rs;

      // ---- P -> LDS: native casts (cvt_pk) packed to one b64 per ch ----
      #pragma unroll
      for (int ch = 0; ch < 4; ch++){
        bf16x4 pk;
        pk[0] = (__bf16)sc[ch][0]; pk[1] = (__bf16)sc[ch][1];
        pk[2] = (__bf16)sc[ch][2]; pk[3] = (__bf16)sc[ch][3];
        *reinterpret_cast<bf16x4*>(PlB + fr * 160 + ch * 32 + fq * 8) = pk;
      }
      bf16x8 pf[2];
      #pragma unroll
      for (int c2 = 0; c2 < 2; c2++)
        pf[c2] = *reinterpret_cast<const bf16x8*>(PlB + fr * 160 + c2 * 64 + fq * 16);

      // ---- PV ----
      #pragma unroll
      for (int dt = 0; dt < 8; dt++)
        #pragma unroll
        for (int c2 = 0; c2 < 2; c2++){
          bf16x8 vf = *reinterpret_cast<const bf16x8*>(
              VlB + (dt * 16 + fr) * 128 + ((c2 * 64 + fq * 16) ^ swz));
          accO[dt] = __builtin_amdgcn_mfma_f32_16x16x32_bf16(pf[c2], vf, accO[dt], 0, 0, 0);
        }
      __syncthreads();
    }

    // ---- epilogue: inv in accO layout ----
    float inv[4];
    #pragma unroll
    for (int i = 0; i < 4; i++) inv[i] = 1.f / __shfl(li, fq * 4 + i);
    #pragma unroll
    for (int dt = 0; dt < 8; dt++)
      #pragma unroll
      for (int i = 0; i < 4; i++){
        int row = qr + fq * 4 + i;
        ob[(size_t)row * DM + h * DK + dt * 16 + fr] = f2bf(accO[dt][i] * inv[i]);
      }
  }
}

extern "C" void kernel_launch(void* const* d_in, const int* in_sizes, int n_in,
                              void* d_out, int out_size, void* d_ws, size_t ws_size,
                              hipStream_t stream){
  const float* x  = (const float*)d_in[0];
  const float* wq = (const float*)d_in[1];
  const float* wk = (const float*)d_in[2];
  const float* wv = (const float*)d_in[3];
  const float* wo = (const float*)d_in[4];
  const int* pos  = (const int*)d_in[5];
  float* out = (float*)d_out;

  char* ws = (char*)d_ws;
  ushort* xb   = (ushort*)(ws);               // 16 MiB; Ob aliases after GEMMs consume xb
  ushort* Ob   = xb;
  ushort* wqkv = (ushort*)(ws + 16777216);    // 24 MiB
  ushort* Qh   = (ushort*)(ws + 41943040);    // 16 MiB
  ushort* Kh   = (ushort*)(ws + 58720256);    // 16 MiB
  ushort* Vt   = (ushort*)(ws + 75497472);    // 16 MiB
  float2* cs   = (float2*)(ws + 92274688);    // 1 MiB
  ushort* wob  = (ushort*)(ws + 93323264);    // 8 MiB

  k_rope_table<<<(S_LEN * 64) / 256, 256, 0, stream>>>(pos, cs);
  k_conv<<<24576, 256, 0, stream>>>(x, wq, wk, wv, wo, xb, wqkv, wob);

  k_gemm_qk<<<256, 512, 0, stream>>>(xb, wqkv, cs, Qh, Kh);
  k_gemm_v<<<256, 512, 0, stream>>>(xb, wqkv + (size_t)2 * DM * DM, Vt);

  k_attn<<<512, 256, 0, stream>>>(Qh, Kh, Vt, Ob);

  k_gemm_wo<<<256, 512, 0, stream>>>(Ob, wob, out);
}

// Round 17
// 237.130 us; speedup vs baseline: 1.1749x; 1.0263x over previous
//
#include <hip/hip_runtime.h>

#define S_LEN 2048
#define DM 2048
#define NH 16
#define DK 128
#define BB 2
#define BH (BB*NH)
#define GK 2048

typedef float f32x4 __attribute__((ext_vector_type(4)));
typedef __bf16 bf16x8 __attribute__((ext_vector_type(8)));
typedef __bf16 bf16x4 __attribute__((ext_vector_type(4)));
typedef unsigned int u32;

#define AS1 __attribute__((address_space(1)))
#define AS3 __attribute__((address_space(3)))

__device__ inline void gload16(const void* g, void* l){
  __builtin_amdgcn_global_load_lds((AS1 const u32*)g, (AS3 u32*)l, 16, 0, 0);
}

__device__ inline ushort f2bf(float f){
  __bf16 h = (__bf16)f;
  ushort u;
  __builtin_memcpy(&u, &h, 2);
  return u;
}

// ---------------- all fp32->bf16 conversions + rope table in one launch ----------------
// blocks < 24576: conversions (float4 regions of 1M: 0,1=x; 2..4=wq/wk/wv; 5=wo).
// blocks >= 24576 (512 blocks): rope cos/sin table [S][64] float2.
__global__ void k_conv(const float* __restrict__ x, const float* __restrict__ wq,
                       const float* __restrict__ wk, const float* __restrict__ wv,
                       const float* __restrict__ wo4,
                       ushort* __restrict__ xb, ushort* __restrict__ dqkv,
                       ushort* __restrict__ dwo,
                       const int* __restrict__ pos, float2* __restrict__ cs){
  int bid = blockIdx.x;
  if (bid >= 24576){
    int idx = (bid - 24576) * 256 + threadIdx.x;   // < 131072 = S*64
    int s = idx >> 6, i = idx & 63;
    float inv = expf(-0.14391156831212787f * (float)i);   // 10000^(-i/64)
    float f = (float)pos[s] * inv;
    cs[idx] = make_float2(cosf(f), sinf(f));
    return;
  }
  int i = bid * 256 + threadIdx.x;    // 0 .. 6M-1 (float4 units)
  int sel = i >> 20;
  int off = i & ((1 << 20) - 1);
  const float* s; ushort* d;
  if (sel < 2){ s = x + ((size_t)sel << 22); d = xb + ((size_t)sel << 22); }
  else if (sel == 2){ s = wq; d = dqkv; }
  else if (sel == 3){ s = wk; d = dqkv + (size_t)DM * DM; }
  else if (sel == 4){ s = wv; d = dqkv + (size_t)2 * DM * DM; }
  else { s = wo4; d = dwo; }
  float4 v = reinterpret_cast<const float4*>(s)[off];
  ushort4 o;
  o.x = f2bf(v.x); o.y = f2bf(v.y); o.z = f2bf(v.z); o.w = f2bf(v.w);
  reinterpret_cast<ushort4*>(d)[off] = o;
}

#define SBAR() do{ __builtin_amdgcn_s_barrier(); __builtin_amdgcn_sched_barrier(0); }while(0)
#define VMC(n) asm volatile("s_waitcnt vmcnt(" #n ")" ::: "memory")

// ================= Q+K GEMM: 256x256 tile, BK=64, 8 waves, 8-phase =================
#define STG(slot, srcp, tks, khh) do{ \
  const ushort* _s = (srcp) + (tks)*64 + (khh)*32; \
  gload16(_s,                    lds + (slot)*8192 + wid*512); \
  gload16(_s + (size_t)128*GK,   lds + (slot)*8192 + 4096 + wid*512); \
}while(0)

#define RD_A(slot, mh) do{ \
  af[0] = *reinterpret_cast<const bf16x8*>(ldsc + (slot)*16384 + wm*8192 + ((mh)*4+0)*1024 + frA); \
  af[1] = *reinterpret_cast<const bf16x8*>(ldsc + (slot)*16384 + wm*8192 + ((mh)*4+1)*1024 + frA); \
  af[2] = *reinterpret_cast<const bf16x8*>(ldsc + (slot)*16384 + wm*8192 + ((mh)*4+2)*1024 + frA); \
  af[3] = *reinterpret_cast<const bf16x8*>(ldsc + (slot)*16384 + wm*8192 + ((mh)*4+3)*1024 + frA); \
}while(0)

#define RD_B(slot) do{ \
  bfr[0] = *reinterpret_cast<const bf16x8*>(ldsc + (slot)*16384 + wn*4096 + 0*1024 + frA); \
  bfr[1] = *reinterpret_cast<const bf16x8*>(ldsc + (slot)*16384 + wn*4096 + 1*1024 + frA); \
  bfr[2] = *reinterpret_cast<const bf16x8*>(ldsc + (slot)*16384 + wn*4096 + 2*1024 + frA); \
  bfr[3] = *reinterpret_cast<const bf16x8*>(ldsc + (slot)*16384 + wn*4096 + 3*1024 + frA); \
}while(0)

#define MM(mh) do{ \
  __builtin_amdgcn_s_setprio(1); \
  _Pragma("unroll") \
  for (int mf2 = 0; mf2 < 4; mf2++) \
    _Pragma("unroll") \
    for (int nf = 0; nf < 4; nf++) \
      acc[(mh)*4+mf2][nf] = __builtin_amdgcn_mfma_f32_16x16x32_bf16(af[mf2], bfr[nf], acc[(mh)*4+mf2][nf], 0, 0, 0); \
  __builtin_amdgcn_s_setprio(0); \
}while(0)

__launch_bounds__(512, 2)
__global__ void k_gemm_qk(const ushort* __restrict__ A, const ushort* __restrict__ Bt,
                          const float2* __restrict__ cs,
                          ushort* __restrict__ Qh, ushort* __restrict__ Kh){
  __shared__ short lds[65536];   // 128 KiB: 8 half-slots x 16 KB
  const int tid = threadIdx.x, lane = tid & 63, wid = tid >> 6;
  const int wm = wid >> 2, wn = wid & 3;
  const int fr = lane & 15, fq = lane >> 4;

  const int bid = blockIdx.x;                  // 256 = 8*32, bijective XCD swizzle
  const int b2 = (bid & 7) * 32 + (bid >> 3);
  const int by = b2 >> 4, bx = b2 & 15;

  const int rbase = wid * 16 + (lane >> 2);
  const int kup = ((lane & 3) ^ ((lane >> 3) & 3)) * 8;
  const ushort* pa = A  + (size_t)(by * 256 + rbase) * GK + kup;
  const ushort* pb = Bt + (size_t)(bx * 256 + rbase) * GK + kup;

  const char* ldsc = (const char*)lds;
  const int frA = fr * 64 + ((fq * 16) ^ (((fr >> 1) & 3) << 4));

  f32x4 acc[8][4] = {};
  bf16x8 af[4], bfr[4];

  STG(0, pa, 0, 0); STG(1, pb, 0, 0); STG(2, pa, 0, 1); STG(3, pb, 0, 1);
  STG(4, pa, 1, 0); STG(5, pb, 1, 0);
  VMC(8);
  SBAR();

  #pragma unroll 1
  for (int it = 0; it < 16; ++it){
    const int tb  = 2 * it + 1;
    const int tn  = (2 * it + 2 < 32) ? 2 * it + 2 : 31;
    const int tn1 = (2 * it + 3 < 32) ? 2 * it + 3 : 31;
    RD_A(0, 0); RD_B(1); STG(6, pa, tb, 1);           SBAR(); MM(0); SBAR();
    RD_A(0, 1);          STG(7, pb, tb, 1);  VMC(6);  SBAR(); MM(1); SBAR();
    RD_A(2, 0); RD_B(3); STG(0, pa, tn, 0);           SBAR(); MM(0); SBAR();
    RD_A(2, 1);          STG(1, pb, tn, 0);  VMC(6);  SBAR(); MM(1); SBAR();
    RD_A(4, 0); RD_B(5); STG(2, pa, tn, 1);           SBAR(); MM(0); SBAR();
    RD_A(4, 1);          STG(3, pb, tn, 1);  VMC(6);  SBAR(); MM(1); SBAR();
    RD_A(6, 0); RD_B(7); STG(4, pa, tn1, 0);          SBAR(); MM(0); SBAR();
    RD_A(6, 1);          STG(5, pb, tn1, 0); VMC(6);  SBAR(); MM(1); SBAR();
  }

  const int rowb = by * 256 + wm * 128 + fq * 4;
  const bool isQ = (bx < 8);
  ushort* dst = isQ ? Qh : Kh;
  const float qscl = isQ ? 0.08838834764831845f : 1.0f;
  #pragma unroll
  for (int mf = 0; mf < 8; mf++)
    #pragma unroll
    for (int nf = 0; nf < 4; nf++){
      int col = bx * 256 + wn * 64 + nf * 16 + fr;
      int cg = col & 2047;
      int hh = cg >> 7, dd = cg & 127, jj = (cg >> 1) & 63;
      #pragma unroll
      for (int i = 0; i < 4; i++){
        int row = rowb + mf * 16 + i;
        int s = row & (S_LEN - 1), bb = row >> 11;
        float2 c2 = cs[s * 64 + jj];
        float v = acc[mf][nf][i];
        float p = __shfl_xor(v, 1);
        float o = (fr & 1) ? fmaf(p, c2.y, v * c2.x) : fmaf(v, c2.x, -p * c2.y);
        dst[((size_t)(bb * NH + hh) * S_LEN + s) * DK + dd] = f2bf(o * qscl);
      }
    }
}

// ================= 256x128 8-phase skeleton (shared by V GEMM and WO GEMM) =================
#define WSTG_A(si, tks, khh) do{ \
  const ushort* _s = pa + (tks)*64 + (khh)*32; \
  gload16(_s,                  lds + (si)*8192 + wid*512); \
  gload16(_s + (size_t)128*GK, lds + (si)*8192 + 4096 + wid*512); \
}while(0)
#define WSTG_B(si, tks, khh) do{ \
  const ushort* _s = pb + (tks)*64 + (khh)*32; \
  gload16(_s, lds + 32768 + (si)*4096 + wid*512); \
}while(0)
#define WRD_A(si, mhf) do{ \
  af[0] = *reinterpret_cast<const bf16x8*>(ldsc + (si)*16384 + wm*4096 + ((mhf)*2+0)*1024 + frA); \
  af[1] = *reinterpret_cast<const bf16x8*>(ldsc + (si)*16384 + wm*4096 + ((mhf)*2+1)*1024 + frA); \
}while(0)
#define WRD_B(si) do{ \
  bfr[0] = *reinterpret_cast<const bf16x8*>(ldsc + 65536 + (si)*8192 + wn*4096 + 0*1024 + frA); \
  bfr[1] = *reinterpret_cast<const bf16x8*>(ldsc + 65536 + (si)*8192 + wn*4096 + 1*1024 + frA); \
  bfr[2] = *reinterpret_cast<const bf16x8*>(ldsc + 65536 + (si)*8192 + wn*4096 + 2*1024 + frA); \
  bfr[3] = *reinterpret_cast<const bf16x8*>(ldsc + 65536 + (si)*8192 + wn*4096 + 3*1024 + frA); \
}while(0)
#define WMM(mhf) do{ \
  __builtin_amdgcn_s_setprio(1); \
  _Pragma("unroll") \
  for (int k2 = 0; k2 < 2; k2++) \
    _Pragma("unroll") \
    for (int nf = 0; nf < 4; nf++) \
      acc[(mhf)*2+k2][nf] = __builtin_amdgcn_mfma_f32_16x16x32_bf16(af[k2], bfr[nf], acc[(mhf)*2+k2][nf], 0, 0, 0); \
  __builtin_amdgcn_s_setprio(0); \
}while(0)

#define WBODY() \
  WSTG_A(0, 0, 0); WSTG_B(0, 0, 0); WSTG_A(1, 0, 1); WSTG_B(1, 0, 1); \
  WSTG_A(2, 1, 0); WSTG_B(2, 1, 0); \
  VMC(6); \
  SBAR(); \
  _Pragma("unroll 1") \
  for (int it = 0; it < 16; ++it){ \
    const int tb  = 2 * it + 1; \
    const int tn  = (2 * it + 2 < 32) ? 2 * it + 2 : 31; \
    const int tn1 = (2 * it + 3 < 32) ? 2 * it + 3 : 31; \
    WRD_A(0, 0); WRD_B(0); WSTG_A(3, tb, 1);            SBAR(); WMM(0); SBAR(); \
    WRD_A(0, 1);           WSTG_B(3, tb, 1);  VMC(6);   SBAR(); WMM(1); SBAR(); \
    WRD_A(1, 0); WRD_B(1); WSTG_A(0, tn, 0);            SBAR(); WMM(0); SBAR(); \
    WRD_A(1, 1);           WSTG_B(0, tn, 0);  VMC(6);   SBAR(); WMM(1); SBAR(); \
    WRD_A(2, 0); WRD_B(2); WSTG_A(1, tn, 1);            SBAR(); WMM(0); SBAR(); \
    WRD_A(2, 1);           WSTG_B(1, tn, 1);  VMC(6);   SBAR(); WMM(1); SBAR(); \
    WRD_A(3, 0); WRD_B(3); WSTG_A(2, tn1, 0);           SBAR(); WMM(0); SBAR(); \
    WRD_A(3, 1);           WSTG_B(2, tn1, 0); VMC(6);   SBAR(); WMM(1); SBAR(); \
  }

__launch_bounds__(512, 2)
__global__ void k_gemm_v(const ushort* __restrict__ A, const ushort* __restrict__ Bt,
                         ushort* __restrict__ Vt){
  __shared__ short lds[49152];   // 96 KiB
  const int tid = threadIdx.x, lane = tid & 63, wid = tid >> 6;
  const int wm = wid >> 1, wn = wid & 1;
  const int fr = lane & 15, fq = lane >> 4;

  const int bid = blockIdx.x;
  const int b2 = (bid & 7) * 32 + (bid >> 3);
  const int by = b2 >> 4, bx = b2 & 15;

  const int rbase = wid * 16 + (lane >> 2);
  const int kup = ((lane & 3) ^ ((lane >> 3) & 3)) * 8;
  const ushort* pa = A  + (size_t)(by * 256 + rbase) * GK + kup;
  const ushort* pb = Bt + (size_t)(bx * 128 + rbase) * GK + kup;

  const char* ldsc = (const char*)lds;
  const int frA = fr * 64 + ((fq * 16) ^ (((fr >> 1) & 3) << 4));

  f32x4 acc[4][4] = {};
  bf16x8 af[2], bfr[4];

  WBODY();

  const int rowb = by * 256 + wm * 64 + fq * 4;
  #pragma unroll
  for (int mf = 0; mf < 4; mf++){
    int row0 = rowb + mf * 16;
    int s0 = row0 & (S_LEN - 1), bb = row0 >> 11;
    #pragma unroll
    for (int nf = 0; nf < 4; nf++){
      int col = bx * 128 + wn * 64 + nf * 16 + fr;
      int hh = col >> 7, dd = col & 127;
      ushort4 o;
      o.x = f2bf(acc[mf][nf][0]); o.y = f2bf(acc[mf][nf][1]);
      o.z = f2bf(acc[mf][nf][2]); o.w = f2bf(acc[mf][nf][3]);
      *reinterpret_cast<ushort4*>(&Vt[((size_t)(bb * NH + hh) * DK + dd) * S_LEN + s0]) = o;
    }
  }
}

__launch_bounds__(512, 2)
__global__ void k_gemm_wo(const ushort* __restrict__ A, const ushort* __restrict__ Bt,
                          float* __restrict__ C){
  __shared__ short lds[49152];   // 96 KiB
  const int tid = threadIdx.x, lane = tid & 63, wid = tid >> 6;
  const int wm = wid >> 1, wn = wid & 1;
  const int fr = lane & 15, fq = lane >> 4;

  const int bid = blockIdx.x;
  const int b2 = (bid & 7) * 32 + (bid >> 3);
  const int by = b2 >> 4, bx = b2 & 15;

  const int rbase = wid * 16 + (lane >> 2);
  const int kup = ((lane & 3) ^ ((lane >> 3) & 3)) * 8;
  const ushort* pa = A  + (size_t)(by * 256 + rbase) * GK + kup;
  const ushort* pb = Bt + (size_t)(bx * 128 + rbase) * GK + kup;

  const char* ldsc = (const char*)lds;
  const int frA = fr * 64 + ((fq * 16) ^ (((fr >> 1) & 3) << 4));

  f32x4 acc[4][4] = {};
  bf16x8 af[2], bfr[4];

  WBODY();

  const int orow = by * 256 + wm * 64 + fq * 4;
  const int ocol = bx * 128 + wn * 64 + fr;
  #pragma unroll
  for (int mf = 0; mf < 4; mf++)
    #pragma unroll
    for (int nf = 0; nf < 4; nf++)
      #pragma unroll
      for (int i = 0; i < 4; i++)
        C[(size_t)(orow + mf * 16 + i) * DM + ocol + nf * 16] = acc[mf][nf][i];
}

// ---------------- causal flash attention: 4 waves x 16 q-rows, 64-row paired chunks ----------------
// r16 structure; K swizzle key fixed: chunk key = (row&6)<<1 (bits 2-3) instead of (row&7)
// (bits 1-2 collided with fq -> 4-way conflicts on half the bank slots). Now exactly 2-way
// everywhere (free per m136). Applied to staging SOURCE (kco) and read offset (kswz) - rule #21.
__launch_bounds__(256, 2)
__global__ void k_attn(const ushort* __restrict__ Q, const ushort* __restrict__ K,
                       const ushort* __restrict__ Vt, ushort* __restrict__ O){
  __shared__ short Kt[2][64 * 128];   // [kv][d] swizzled (16KB each)
  __shared__ short Vl[2][128 * 64];   // [d][kv] swizzled (16KB each)
  __shared__ short Pl[4][16 * 80];    // per-wave P, 160B row stride (2.5KB each)
  const int tid = threadIdx.x, lane = tid & 63, wid = tid >> 6;
  const int bid = blockIdx.x;
  const int pid = bid >> 5;           // 0..15
  const int bh = bid & 31;
  const int b = bh >> 4, h = bh & 15;
  const int fr = lane & 15, fq = lane >> 4;
  const int kswz = (fr & 6) << 5;     // K chunk key (row&6)<<1, byte units
  const int vswz = (fr & 7) << 4;     // V key unchanged (2-way verified)

  const ushort* kb = K  + (size_t)bh * S_LEN * DK;
  const ushort* vb = Vt + (size_t)bh * DK * S_LEN;
  char* PlB = (char*)Pl + wid * 2560;
  ushort* ob = O + (size_t)b * S_LEN * DM;

  // staging: 4 waves x 4 instrs for K and V (16KB tile each)
  int kro[4], kco[4], vro[4], vco[4];
  #pragma unroll
  for (int jj = 0; jj < 4; jj++){
    int ins = wid * 4 + jj;
    kro[jj] = ins * 4 + (lane >> 4);
    kco[jj] = 8 * ((lane & 15) ^ ((kro[jj] & 6) << 1));
    vro[jj] = ins * 8 + (lane >> 3);
    vco[jj] = 8 * ((lane & 7) ^ (vro[jj] & 7));
  }

  #pragma unroll 1
  for (int half = 0; half < 2; half++){
    const int j = half ? pid : 31 - pid;      // 64-row chunk index, 0..31
    const int qr = j * 64 + wid * 16;
    const int nt = j + 1;                     // kv tiles of 64

    bf16x8 qf[4];
    #pragma unroll
    for (int c = 0; c < 4; c++)
      qf[c] = *reinterpret_cast<const bf16x8*>(
          Q + ((size_t)bh * S_LEN + qr + fr) * DK + c * 32 + fq * 8);

    float mi = -1e30f, li = 0.f;     // per-lane scalars: q-row = qr + fr
    f32x4 accO[8] = {};

    __syncthreads();                  // protect buffers from previous half's readers
    {
      char* kd = (char*)Kt;
      char* vd = (char*)Vl;
      #pragma unroll
      for (int jj = 0; jj < 4; jj++){
        int ins = wid * 4 + jj;
        gload16(kb + (size_t)kro[jj] * DK + kco[jj],      kd + ins * 1024);
        gload16(vb + (size_t)vro[jj] * S_LEN + vco[jj],   vd + ins * 1024);
      }
    }
    __syncthreads();

    #pragma unroll 1
    for (int kt = 0; kt < nt; kt++){
      const int k0 = kt * 64;
      const int cur = kt & 1;
      if (kt + 1 < nt){
        const int k1 = k0 + 64;
        char* kd = (char*)Kt + (cur ^ 1) * 16384;
        char* vd = (char*)Vl + (cur ^ 1) * 16384;
        #pragma unroll
        for (int jj = 0; jj < 4; jj++){
          int ins = wid * 4 + jj;
          gload16(kb + (size_t)(k1 + kro[jj]) * DK + kco[jj],  kd + ins * 1024);
          gload16(vb + (size_t)vro[jj] * S_LEN + k1 + vco[jj], vd + ins * 1024);
        }
      }
      const char* KtB = (const char*)Kt + cur * 16384;
      const char* VlB = (const char*)Vl + cur * 16384;

      // ---- swapped QK^T (Q pre-scaled): lane owns q=fr, kv=16ch+4fq+i ----
      f32x4 sc[4] = {};
      #pragma unroll
      for (int c = 0; c < 4; c++){
        bf16x8 kf[4];
        #pragma unroll
        for (int ch = 0; ch < 4; ch++)
          kf[ch] = *reinterpret_cast<const bf16x8*>(
              KtB + (ch * 16 + fr) * 256 + ((c * 64 + fq * 16) ^ kswz));
        #pragma unroll
        for (int ch = 0; ch < 4; ch++)
          sc[ch] = __builtin_amdgcn_mfma_f32_16x16x32_bf16(kf[ch], qf[c], sc[ch], 0, 0, 0);
      }

      // ---- causal mask on last tile (kv = k0+16ch+4fq+i vs q = qr+fr) ----
      const int qrow = qr + fr;
      if (kt == nt - 1){
        #pragma unroll
        for (int ch = 0; ch < 4; ch++)
          #pragma unroll
          for (int i = 0; i < 4; i++)
            if (k0 + ch * 16 + fq * 4 + i > qrow) sc[ch][i] = -1e30f;
      }

      // ---- in-register row max + 2 shfl ----
      float mx = sc[0][0];
      #pragma unroll
      for (int ch = 0; ch < 4; ch++)
        #pragma unroll
        for (int i = 0; i < 4; i++) mx = fmaxf(mx, sc[ch][i]);
      mx = fmaxf(mx, __shfl_xor(mx, 16));
      mx = fmaxf(mx, __shfl_xor(mx, 32));

      // ---- T13 defer-max ----
      if (!__all(mx <= mi + 8.0f)){
        float mn = fmaxf(mi, mx);
        float scl = __expf(mi - mn);
        mi = mn;
        li *= scl;
        float sclq[4];
        #pragma unroll
        for (int i = 0; i < 4; i++) sclq[i] = __shfl(scl, fq * 4 + i);
        #pragma unroll
        for (int dt = 0; dt < 8; dt++)
          #pragma unroll
          for (int i = 0; i < 4; i++) accO[dt][i] *= sclq[i];
      }

      float rs = 0.f;
      #pragma unroll
      for (int ch = 0; ch < 4; ch++)
        #pragma unroll
        for (int i = 0; i < 4; i++){
          float e = __expf(sc[ch][i] - mi);
          sc[ch][i] = e;
          rs += e;
        }
      rs += __shfl_xor(rs, 16);
      rs += __shfl_xor(rs, 32);
      li += rs;

      // ---- P -> LDS: native casts (cvt_pk) packed to one b64 per ch ----
      #pragma unroll
      for (int ch = 0; ch < 4; ch++){
        bf16x4 pk;
        pk[0] = (__bf16)sc[ch][0]; pk[1] = (__bf16)sc[ch][1];
        pk[2] = (__bf16)sc[ch][2]; pk[3] = (__bf16)sc[ch][3];
        *reinterpret_cast<bf16x4*>(PlB + fr * 160 + ch * 32 + fq * 8) = pk;
      }
      bf16x8 pf[2];
      #pragma unroll
      for (int c2 = 0; c2 < 2; c2++)
        pf[c2] = *reinterpret_cast<const bf16x8*>(PlB + fr * 160 + c2 * 64 + fq * 16);

      // ---- PV ----
      #pragma unroll
      for (int dt = 0; dt < 8; dt++)
        #pragma unroll
        for (int c2 = 0; c2 < 2; c2++){
          bf16x8 vf = *reinterpret_cast<const bf16x8*>(
              VlB + (dt * 16 + fr) * 128 + ((c2 * 64 + fq * 16) ^ vswz));
          accO[dt] = __builtin_amdgcn_mfma_f32_16x16x32_bf16(pf[c2], vf, accO[dt], 0, 0, 0);
        }
      __syncthreads();
    }

    // ---- epilogue: inv in accO layout ----
    float inv[4];
    #pragma unroll
    for (int i = 0; i < 4; i++) inv[i] = 1.f / __shfl(li, fq * 4 + i);
    #pragma unroll
    for (int dt = 0; dt < 8; dt++)
      #pragma unroll
      for (int i = 0; i < 4; i++){
        int row = qr + fq * 4 + i;
        ob[(size_t)row * DM + h * DK + dt * 16 + fr] = f2bf(accO[dt][i] * inv[i]);
      }
  }
}

extern "C" void kernel_launch(void* const* d_in, const int* in_sizes, int n_in,
                              void* d_out, int out_size, void* d_ws, size_t ws_size,
                              hipStream_t stream){
  const float* x  = (const float*)d_in[0];
  const float* wq = (const float*)d_in[1];
  const float* wk = (const float*)d_in[2];
  const float* wv = (const float*)d_in[3];
  const float* wo = (const float*)d_in[4];
  const int* pos  = (const int*)d_in[5];
  float* out = (float*)d_out;

  char* ws = (char*)d_ws;
  ushort* xb   = (ushort*)(ws);               // 16 MiB; Ob aliases after GEMMs consume xb
  ushort* Ob   = xb;
  ushort* wqkv = (ushort*)(ws + 16777216);    // 24 MiB
  ushort* Qh   = (ushort*)(ws + 41943040);    // 16 MiB
  ushort* Kh   = (ushort*)(ws + 58720256);    // 16 MiB
  ushort* Vt   = (ushort*)(ws + 75497472);    // 16 MiB
  float2* cs   = (float2*)(ws + 92274688);    // 1 MiB
  ushort* wob  = (ushort*)(ws + 93323264);    // 8 MiB

  k_conv<<<24576 + 512, 256, 0, stream>>>(x, wq, wk, wv, wo, xb, wqkv, wob, pos, cs);

  k_gemm_qk<<<256, 512, 0, stream>>>(xb, wqkv, cs, Qh, Kh);
  k_gemm_v<<<256, 512, 0, stream>>>(xb, wqkv + (size_t)2 * DM * DM, Vt);

  k_attn<<<512, 256, 0, stream>>>(Qh, Kh, Vt, Ob);

  k_gemm_wo<<<256, 512, 0, stream>>>(Ob, wob, out);
}